// Round 2
// baseline (2725.316 us; speedup 1.0000x reference)
//
#include <hip/hip_runtime.h>
#include <math.h>

// GCN: 3x (X@W -> scale by norm_src -> gather-sum over in-edges -> *norm_dst + b -> relu)
// then mean-pool per graph, linear to 16 classes, log_softmax.

#define HID 256

// ---------------- degree count ----------------
__global__ void k_degree(const int* __restrict__ src, const int* __restrict__ dst,
                         int* __restrict__ outd, int* __restrict__ ind, int E) {
    int i = blockIdx.x * blockDim.x + threadIdx.x;
    int stride = gridDim.x * blockDim.x;
    for (; i < E; i += stride) {
        atomicAdd(&outd[src[i]], 1);
        atomicAdd(&ind[dst[i]], 1);
    }
}

// ---------------- norms ----------------
__global__ void k_norm(const int* __restrict__ outd, const int* __restrict__ ind,
                       float* __restrict__ ns, float* __restrict__ nd, int N) {
    int i = blockIdx.x * blockDim.x + threadIdx.x;
    if (i < N) {
        int od = outd[i], id = ind[i];
        ns[i] = od > 0 ? rsqrtf((float)od) : 0.f;
        nd[i] = id > 0 ? rsqrtf((float)id) : 0.f;
    }
}

// ---------------- exclusive scan of in-degree -> offsets[N+1] (single block) ----------------
__global__ __launch_bounds__(1024) void k_scan(const int* __restrict__ ind,
                                               int* __restrict__ offs, int N) {
    __shared__ int s[1024];
    int t = threadIdx.x;
    int chunk = (N + 1023) / 1024;
    int lo = t * chunk;
    int hi = min(N, lo + chunk);
    int sum = 0;
    for (int i = lo; i < hi; ++i) sum += ind[i];
    s[t] = sum;
    __syncthreads();
    for (int off = 1; off < 1024; off <<= 1) {
        int v = (t >= off) ? s[t - off] : 0;
        __syncthreads();
        s[t] += v;
        __syncthreads();
    }
    int base = (t == 0) ? 0 : s[t - 1];
    for (int i = lo; i < hi; ++i) { offs[i] = base; base += ind[i]; }
    if (t == 1023) offs[N] = s[1023];
}

// ---------------- CSR fill (by dst) ----------------
__global__ void k_fill(const int* __restrict__ src, const int* __restrict__ dst,
                       const int* __restrict__ offs, int* __restrict__ cnt,
                       int* __restrict__ csr, int E) {
    int i = blockIdx.x * blockDim.x + threadIdx.x;
    int stride = gridDim.x * blockDim.x;
    for (; i < E; i += stride) {
        int d = dst[i];
        int p = offs[d] + atomicAdd(&cnt[d], 1);
        csr[p] = src[i];
    }
}

// ---------------- GEMM: C[M,256] = A[M,256] @ B[256,256], rows scaled by ns ----------------
__global__ __launch_bounds__(256) void k_gemm(const float* __restrict__ A,
                                              const float* __restrict__ B,
                                              const float* __restrict__ ns,
                                              float* __restrict__ C, int M) {
    __shared__ float As[16][68];
    __shared__ float Bs[16][68];
    int tid = threadIdx.x;
    int tx = tid & 15, ty = tid >> 4;   // 16 x 16 threads
    int row0 = blockIdx.x * 64;
    int col0 = blockIdx.y * 64;
    float c[4][4] = {};
    for (int k0 = 0; k0 < 256; k0 += 16) {
        {   // A tile 64x16, transpose into As[k][m]
            int r = tid >> 2;
            int kk = (tid & 3) * 4;
            int grow = row0 + r;
            float4 a = make_float4(0.f, 0.f, 0.f, 0.f);
            if (grow < M) a = *(const float4*)&A[(size_t)grow * 256 + k0 + kk];
            As[kk + 0][r] = a.x; As[kk + 1][r] = a.y;
            As[kk + 2][r] = a.z; As[kk + 3][r] = a.w;
        }
        {   // B tile 16x64
            int r = tid >> 4;
            int cc = (tid & 15) * 4;
            *(float4*)&Bs[r][cc] = *(const float4*)&B[(size_t)(k0 + r) * 256 + col0 + cc];
        }
        __syncthreads();
#pragma unroll
        for (int k = 0; k < 16; ++k) {
            float4 a4 = *(float4*)&As[k][ty * 4];
            float4 b4 = *(float4*)&Bs[k][tx * 4];
            float av[4] = {a4.x, a4.y, a4.z, a4.w};
            float bv[4] = {b4.x, b4.y, b4.z, b4.w};
#pragma unroll
            for (int i = 0; i < 4; ++i)
#pragma unroll
                for (int j = 0; j < 4; ++j)
                    c[i][j] = fmaf(av[i], bv[j], c[i][j]);
        }
        __syncthreads();
    }
#pragma unroll
    for (int i = 0; i < 4; ++i) {
        int grow = row0 + ty * 4 + i;
        if (grow < M) {
            float s = ns ? ns[grow] : 1.f;
            float4 v = make_float4(c[i][0] * s, c[i][1] * s, c[i][2] * s, c[i][3] * s);
            *(float4*)&C[(size_t)grow * 256 + col0 + tx * 4] = v;
        }
    }
}

// ---------------- aggregate: out[n] = relu(nd[n] * sum_{e in in(n)} h[src(e)] + b) ----------------
__global__ __launch_bounds__(256) void k_agg(const float* __restrict__ h,
                                             const int* __restrict__ csr,
                                             const int* __restrict__ offs,
                                             const float* __restrict__ nd,
                                             const float* __restrict__ bias,
                                             float* __restrict__ out, int N) {
    int wave = threadIdx.x >> 6;
    int lane = threadIdx.x & 63;
    int node = blockIdx.x * 4 + wave;
    if (node >= N) return;
    int e0 = offs[node], e1 = offs[node + 1];
    int c = lane * 4;
    float4 acc = make_float4(0.f, 0.f, 0.f, 0.f);
    for (int e = e0; e < e1; ++e) {
        int s = csr[e];
        float4 v = *(const float4*)&h[(size_t)s * 256 + c];
        acc.x += v.x; acc.y += v.y; acc.z += v.z; acc.w += v.w;
    }
    float sc = nd[node];
    float4 b = *(const float4*)&bias[c];
    float4 r;
    r.x = fmaxf(fmaf(acc.x, sc, b.x), 0.f);
    r.y = fmaxf(fmaf(acc.y, sc, b.y), 0.f);
    r.z = fmaxf(fmaf(acc.z, sc, b.z), 0.f);
    r.w = fmaxf(fmaf(acc.w, sc, b.w), 0.f);
    *(float4*)&out[(size_t)node * 256 + c] = r;
}

// ---------------- pool + linear + log_softmax ----------------
__global__ __launch_bounds__(256) void k_pool(const float* __restrict__ h,
                                              const int* __restrict__ gid,
                                              const float* __restrict__ Wlin,
                                              const float* __restrict__ blin,
                                              float* __restrict__ out, int N) {
    int g = blockIdx.x;
    int t = threadIdx.x;
    // lower_bound(g), lower_bound(g+1) over sorted gid
    int s, e;
    {
        int lo = 0, hi = N;
        while (lo < hi) { int m = (lo + hi) >> 1; if (gid[m] < g) lo = m + 1; else hi = m; }
        s = lo;
        lo = s; hi = N;
        while (lo < hi) { int m = (lo + hi) >> 1; if (gid[m] < g + 1) lo = m + 1; else hi = m; }
        e = lo;
    }
    float acc = 0.f;
    for (int i = s; i < e; ++i) acc += h[(size_t)i * 256 + t];
    float cntf = (float)((e - s) > 0 ? (e - s) : 1);
    __shared__ float hg[256];
    hg[t] = acc / cntf;
    __syncthreads();
    if (t < 16) {
        float v = blin[t];
        for (int k = 0; k < 256; ++k) v = fmaf(hg[k], Wlin[k * 16 + t], v);
        float m = v;
#pragma unroll
        for (int off = 8; off; off >>= 1) m = fmaxf(m, __shfl_xor(m, off, 16));
        float ex = expf(v - m);
        float ssum = ex;
#pragma unroll
        for (int off = 8; off; off >>= 1) ssum += __shfl_xor(ssum, off, 16);
        out[g * 16 + t] = v - m - logf(ssum);
    }
}

extern "C" void kernel_launch(void* const* d_in, const int* in_sizes, int n_in,
                              void* d_out, int out_size, void* d_ws, size_t ws_size,
                              hipStream_t stream) {
    const float* feats   = (const float*)d_in[0];
    const int*   edge_src= (const int*)d_in[1];
    const int*   edge_dst= (const int*)d_in[2];
    const int*   gid     = (const int*)d_in[3];
    const float* W1 = (const float*)d_in[4];  const float* b1 = (const float*)d_in[5];
    const float* W2 = (const float*)d_in[6];  const float* b2 = (const float*)d_in[7];
    const float* W3 = (const float*)d_in[8];  const float* b3 = (const float*)d_in[9];
    const float* Wlin = (const float*)d_in[10]; const float* blin = (const float*)d_in[11];
    float* out = (float*)d_out;

    const int E = in_sizes[1];
    const int N = in_sizes[3];
    const int G = 256;

    // workspace carve-up
    size_t off = 0;
    auto alloc = [&](size_t bytes) -> void* {
        void* p = (char*)d_ws + off;
        off += (bytes + 255) & ~(size_t)255;
        return p;
    };
    int*   outd = (int*)alloc((size_t)N * 4);
    int*   ind  = (int*)alloc((size_t)N * 4);
    int*   cnt  = (int*)alloc((size_t)N * 4);
    size_t zero_bytes = off;                    // zero the three atomic-counter arrays
    int*   offs = (int*)alloc(((size_t)N + 1) * 4);
    float* ns   = (float*)alloc((size_t)N * 4);
    float* nd   = (float*)alloc((size_t)N * 4);
    int*   csr  = (int*)alloc((size_t)E * 4);
    float* htmp = (float*)alloc((size_t)N * HID * 4);
    float* buf  = (float*)alloc((size_t)N * HID * 4);
    (void)ws_size;

    hipMemsetAsync(d_ws, 0, zero_bytes, stream);

    k_degree<<<2048, 256, 0, stream>>>(edge_src, edge_dst, outd, ind, E);
    k_norm<<<(N + 255) / 256, 256, 0, stream>>>(outd, ind, ns, nd, N);
    k_scan<<<1, 1024, 0, stream>>>(ind, offs, N);
    k_fill<<<2048, 256, 0, stream>>>(edge_src, edge_dst, offs, cnt, csr, E);

    dim3 ggrid((N + 63) / 64, 4);
    int agg_blocks = (N + 3) / 4;

    // layer 1
    k_gemm<<<ggrid, 256, 0, stream>>>(feats, W1, ns, htmp, N);
    k_agg<<<agg_blocks, 256, 0, stream>>>(htmp, csr, offs, nd, b1, buf, N);
    // layer 2
    k_gemm<<<ggrid, 256, 0, stream>>>(buf, W2, ns, htmp, N);
    k_agg<<<agg_blocks, 256, 0, stream>>>(htmp, csr, offs, nd, b2, buf, N);
    // layer 3
    k_gemm<<<ggrid, 256, 0, stream>>>(buf, W3, ns, htmp, N);
    k_agg<<<agg_blocks, 256, 0, stream>>>(htmp, csr, offs, nd, b3, buf, N);

    k_pool<<<G, 256, 0, stream>>>(buf, gid, Wlin, blin, out, N);
    (void)out_size;
}

// Round 3
// 2701.830 us; speedup vs baseline: 1.0087x; 1.0087x over previous
//
#include <hip/hip_runtime.h>
#include <math.h>

// GCN: 3x (X@W -> scale by norm_src -> gather-sum over in-edges -> *norm_dst + b -> relu)
// then mean-pool per graph, linear to 16 classes, log_softmax.

#define HID 256

// ---------------- degree count ----------------
__global__ void k_degree(const int* __restrict__ src, const int* __restrict__ dst,
                         int* __restrict__ outd, int* __restrict__ ind, int E) {
    int i = blockIdx.x * blockDim.x + threadIdx.x;
    int stride = gridDim.x * blockDim.x;
    for (; i < E; i += stride) {
        atomicAdd(&outd[src[i]], 1);
        atomicAdd(&ind[dst[i]], 1);
    }
}

// ---------------- norms ----------------
__global__ void k_norm(const int* __restrict__ outd, const int* __restrict__ ind,
                       float* __restrict__ ns, float* __restrict__ nd, int N) {
    int i = blockIdx.x * blockDim.x + threadIdx.x;
    if (i < N) {
        int od = outd[i], id = ind[i];
        ns[i] = od > 0 ? rsqrtf((float)od) : 0.f;
        nd[i] = id > 0 ? rsqrtf((float)id) : 0.f;
    }
}

// ---------------- exclusive scan of in-degree -> offsets[N+1] (single block) ----------------
__global__ __launch_bounds__(1024) void k_scan(const int* __restrict__ ind,
                                               int* __restrict__ offs, int N) {
    __shared__ int s[1024];
    int t = threadIdx.x;
    int chunk = (N + 1023) / 1024;
    int lo = t * chunk;
    int hi = min(N, lo + chunk);
    int sum = 0;
    for (int i = lo; i < hi; ++i) sum += ind[i];
    s[t] = sum;
    __syncthreads();
    for (int off = 1; off < 1024; off <<= 1) {
        int v = (t >= off) ? s[t - off] : 0;
        __syncthreads();
        s[t] += v;
        __syncthreads();
    }
    int base = (t == 0) ? 0 : s[t - 1];
    for (int i = lo; i < hi; ++i) { offs[i] = base; base += ind[i]; }
    if (t == 1023) offs[N] = s[1023];
}

// ---------------- CSR fill (by dst) ----------------
__global__ void k_fill(const int* __restrict__ src, const int* __restrict__ dst,
                       const int* __restrict__ offs, int* __restrict__ cnt,
                       int* __restrict__ csr, int E) {
    int i = blockIdx.x * blockDim.x + threadIdx.x;
    int stride = gridDim.x * blockDim.x;
    for (; i < E; i += stride) {
        int d = dst[i];
        int p = offs[d] + atomicAdd(&cnt[d], 1);
        csr[p] = src[i];
    }
}

// ---------------- GEMM: C[M,256] = A[M,256] @ B[256,256], rows scaled by ns ----------------
// 128x128 block tile, 256 threads, 8x8 per thread (split 4+4 to kill LDS read conflicts).
__global__ __launch_bounds__(256) void k_gemm(const float* __restrict__ A,
                                              const float* __restrict__ B,
                                              const float* __restrict__ ns,
                                              float* __restrict__ C, int M) {
    __shared__ float As[16][132];   // As[k][m]
    __shared__ float Bs[16][132];   // Bs[k][n]
    int t = threadIdx.x;
    int tx = t & 15, ty = t >> 4;
    int row0 = blockIdx.x * 128;
    int col0 = blockIdx.y * 128;
    float c[8][8] = {};
    for (int k0 = 0; k0 < 256; k0 += 16) {
        // A tile: 128 rows x 16 k. 2 threads per row, 8 k each.
        {
            int ar = t >> 1;
            int ak = (t & 1) * 8;
            int grow = row0 + ar;
            float4 a0 = make_float4(0.f, 0.f, 0.f, 0.f), a1 = a0;
            if (grow < M) {
                a0 = *(const float4*)&A[(size_t)grow * 256 + k0 + ak];
                a1 = *(const float4*)&A[(size_t)grow * 256 + k0 + ak + 4];
            }
            As[ak + 0][ar] = a0.x; As[ak + 1][ar] = a0.y;
            As[ak + 2][ar] = a0.z; As[ak + 3][ar] = a0.w;
            As[ak + 4][ar] = a1.x; As[ak + 5][ar] = a1.y;
            As[ak + 6][ar] = a1.z; As[ak + 7][ar] = a1.w;
        }
        // B tile: 16 k x 128 cols. 16 threads per k-row, 8 cols each.
        {
            int br = t >> 4;
            int bc = (t & 15) * 8;
            float4 b0 = *(const float4*)&B[(size_t)(k0 + br) * 256 + col0 + bc];
            float4 b1 = *(const float4*)&B[(size_t)(k0 + br) * 256 + col0 + bc + 4];
            *(float4*)&Bs[br][bc] = b0;
            *(float4*)&Bs[br][bc + 4] = b1;
        }
        __syncthreads();
#pragma unroll
        for (int k = 0; k < 16; ++k) {
            float a[8], b[8];
            *(float4*)&a[0] = *(float4*)&As[k][ty * 4];
            *(float4*)&a[4] = *(float4*)&As[k][64 + ty * 4];
            *(float4*)&b[0] = *(float4*)&Bs[k][tx * 4];
            *(float4*)&b[4] = *(float4*)&Bs[k][64 + tx * 4];
#pragma unroll
            for (int i = 0; i < 8; ++i)
#pragma unroll
                for (int j = 0; j < 8; ++j)
                    c[i][j] = fmaf(a[i], b[j], c[i][j]);
        }
        __syncthreads();
    }
#pragma unroll
    for (int i = 0; i < 8; ++i) {
        int grow = row0 + ((i < 4) ? (ty * 4 + i) : (64 + ty * 4 + i - 4));
        if (grow < M) {
            float s = ns[grow];
            float4 v0 = make_float4(c[i][0] * s, c[i][1] * s, c[i][2] * s, c[i][3] * s);
            float4 v1 = make_float4(c[i][4] * s, c[i][5] * s, c[i][6] * s, c[i][7] * s);
            *(float4*)&C[(size_t)grow * 256 + col0 + tx * 4] = v0;
            *(float4*)&C[(size_t)grow * 256 + col0 + 64 + tx * 4] = v1;
        }
    }
}

// ---------------- aggregate (column-half pass): out[n, c0:c0+128] ----------------
// One wave handles 2 nodes (32 lanes each, float4/lane = 128 cols).
__global__ __launch_bounds__(256) void k_agg_half(const float* __restrict__ h,
                                                  const int* __restrict__ csr,
                                                  const int* __restrict__ offs,
                                                  const float* __restrict__ nd,
                                                  const float* __restrict__ bias,
                                                  float* __restrict__ out, int N, int c0) {
    int wave = threadIdx.x >> 6;
    int lane = threadIdx.x & 63;
    int half = lane >> 5;
    int l = lane & 31;
    int node = blockIdx.x * 8 + wave * 2 + half;
    if (node >= N) return;
    int e0 = offs[node], e1 = offs[node + 1];
    int c = c0 + l * 4;
    float4 acc = make_float4(0.f, 0.f, 0.f, 0.f);
    for (int e = e0; e < e1; ++e) {
        int s = csr[e];
        float4 v = *(const float4*)&h[(size_t)s * 256 + c];
        acc.x += v.x; acc.y += v.y; acc.z += v.z; acc.w += v.w;
    }
    float sc = nd[node];
    float4 b = *(const float4*)&bias[c];
    float4 r;
    r.x = fmaxf(fmaf(acc.x, sc, b.x), 0.f);
    r.y = fmaxf(fmaf(acc.y, sc, b.y), 0.f);
    r.z = fmaxf(fmaf(acc.z, sc, b.z), 0.f);
    r.w = fmaxf(fmaf(acc.w, sc, b.w), 0.f);
    *(float4*)&out[(size_t)node * 256 + c] = r;
}

// ---------------- pool + linear + log_softmax ----------------
__global__ __launch_bounds__(256) void k_pool(const float* __restrict__ h,
                                              const int* __restrict__ gid,
                                              const float* __restrict__ Wlin,
                                              const float* __restrict__ blin,
                                              float* __restrict__ out, int N) {
    int g = blockIdx.x;
    int t = threadIdx.x;
    int s, e;
    {
        int lo = 0, hi = N;
        while (lo < hi) { int m = (lo + hi) >> 1; if (gid[m] < g) lo = m + 1; else hi = m; }
        s = lo;
        lo = s; hi = N;
        while (lo < hi) { int m = (lo + hi) >> 1; if (gid[m] < g + 1) lo = m + 1; else hi = m; }
        e = lo;
    }
    float acc = 0.f;
    for (int i = s; i < e; ++i) acc += h[(size_t)i * 256 + t];
    float cntf = (float)((e - s) > 0 ? (e - s) : 1);
    __shared__ float hg[256];
    hg[t] = acc / cntf;
    __syncthreads();
    if (t < 16) {
        float v = blin[t];
        for (int k = 0; k < 256; ++k) v = fmaf(hg[k], Wlin[k * 16 + t], v);
        float m = v;
#pragma unroll
        for (int off = 8; off; off >>= 1) m = fmaxf(m, __shfl_xor(m, off, 16));
        float ex = expf(v - m);
        float ssum = ex;
#pragma unroll
        for (int off = 8; off; off >>= 1) ssum += __shfl_xor(ssum, off, 16);
        out[g * 16 + t] = v - m - logf(ssum);
    }
}

extern "C" void kernel_launch(void* const* d_in, const int* in_sizes, int n_in,
                              void* d_out, int out_size, void* d_ws, size_t ws_size,
                              hipStream_t stream) {
    const float* feats   = (const float*)d_in[0];
    const int*   edge_src= (const int*)d_in[1];
    const int*   edge_dst= (const int*)d_in[2];
    const int*   gid     = (const int*)d_in[3];
    const float* W1 = (const float*)d_in[4];  const float* b1 = (const float*)d_in[5];
    const float* W2 = (const float*)d_in[6];  const float* b2 = (const float*)d_in[7];
    const float* W3 = (const float*)d_in[8];  const float* b3 = (const float*)d_in[9];
    const float* Wlin = (const float*)d_in[10]; const float* blin = (const float*)d_in[11];
    float* out = (float*)d_out;

    const int E = in_sizes[1];
    const int N = in_sizes[3];
    const int G = 256;

    size_t off = 0;
    auto alloc = [&](size_t bytes) -> void* {
        void* p = (char*)d_ws + off;
        off += (bytes + 255) & ~(size_t)255;
        return p;
    };
    int*   outd = (int*)alloc((size_t)N * 4);
    int*   ind  = (int*)alloc((size_t)N * 4);
    int*   cnt  = (int*)alloc((size_t)N * 4);
    size_t zero_bytes = off;                    // zero the three atomic-counter arrays
    int*   offs = (int*)alloc(((size_t)N + 1) * 4);
    float* ns   = (float*)alloc((size_t)N * 4);
    float* nd   = (float*)alloc((size_t)N * 4);
    int*   csr  = (int*)alloc((size_t)E * 4);
    float* htmp = (float*)alloc((size_t)N * HID * 4);
    float* buf  = (float*)alloc((size_t)N * HID * 4);
    (void)ws_size;

    hipMemsetAsync(d_ws, 0, zero_bytes, stream);

    k_degree<<<2048, 256, 0, stream>>>(edge_src, edge_dst, outd, ind, E);
    k_norm<<<(N + 255) / 256, 256, 0, stream>>>(outd, ind, ns, nd, N);
    k_scan<<<1, 1024, 0, stream>>>(ind, offs, N);
    k_fill<<<2048, 256, 0, stream>>>(edge_src, edge_dst, offs, cnt, csr, E);

    dim3 ggrid((N + 127) / 128, 2);
    int agg_blocks = (N + 7) / 8;

    // layer 1
    k_gemm<<<ggrid, 256, 0, stream>>>(feats, W1, ns, htmp, N);
    k_agg_half<<<agg_blocks, 256, 0, stream>>>(htmp, csr, offs, nd, b1, buf, N, 0);
    k_agg_half<<<agg_blocks, 256, 0, stream>>>(htmp, csr, offs, nd, b1, buf, N, 128);
    // layer 2
    k_gemm<<<ggrid, 256, 0, stream>>>(buf, W2, ns, htmp, N);
    k_agg_half<<<agg_blocks, 256, 0, stream>>>(htmp, csr, offs, nd, b2, buf, N, 0);
    k_agg_half<<<agg_blocks, 256, 0, stream>>>(htmp, csr, offs, nd, b2, buf, N, 128);
    // layer 3
    k_gemm<<<ggrid, 256, 0, stream>>>(buf, W3, ns, htmp, N);
    k_agg_half<<<agg_blocks, 256, 0, stream>>>(htmp, csr, offs, nd, b3, buf, N, 0);
    k_agg_half<<<agg_blocks, 256, 0, stream>>>(htmp, csr, offs, nd, b3, buf, N, 128);

    k_pool<<<G, 256, 0, stream>>>(buf, gid, Wlin, blin, out, N);
    (void)out_size;
}

// Round 6
// 2438.615 us; speedup vs baseline: 1.1176x; 1.1079x over previous
//
#include <hip/hip_runtime.h>
#include <math.h>

// GCN: 3x (X@W -> scale by norm_src -> gather-sum over in-edges -> *norm_dst + b -> relu)
// then mean-pool per graph, linear to 16 classes, log_softmax.

#define HID 256

// ---------------- degree + rank (rank = in-edge slot via atomic return) ----------------
__global__ void k_degree_rank(const int* __restrict__ src, const int* __restrict__ dst,
                              int* __restrict__ outd, int* __restrict__ ind,
                              int* __restrict__ rank, int E) {
    int tid = blockIdx.x * blockDim.x + threadIdx.x;
    int stride = gridDim.x * blockDim.x;
    int E4 = E >> 2;
    const int4* src4 = (const int4*)src;
    const int4* dst4 = (const int4*)dst;
    int4* rank4 = (int4*)rank;
    for (int i = tid; i < E4; i += stride) {
        int4 s = src4[i], d = dst4[i];
        atomicAdd(&outd[s.x], 1); atomicAdd(&outd[s.y], 1);
        atomicAdd(&outd[s.z], 1); atomicAdd(&outd[s.w], 1);
        int4 r;
        r.x = atomicAdd(&ind[d.x], 1);
        r.y = atomicAdd(&ind[d.y], 1);
        r.z = atomicAdd(&ind[d.z], 1);
        r.w = atomicAdd(&ind[d.w], 1);
        rank4[i] = r;
    }
    for (int i = E4 * 4 + tid; i < E; i += stride) {
        atomicAdd(&outd[src[i]], 1);
        rank[i] = atomicAdd(&ind[dst[i]], 1);
    }
}

// ---------------- scan phase 1: per-block partial sums of in-degree ----------------
__global__ __launch_bounds__(256) void k_scan_part(const int* __restrict__ ind,
                                                   int* __restrict__ part, int N) {
    int b = blockIdx.x, t = threadIdx.x;
    int CH = (N + 255) / 256;
    int lo = b * CH, hi = min(N, lo + CH);
    int s = 0;
    for (int i = lo + t; i < hi; i += 256) s += ind[i];
    __shared__ int sm[256];
    sm[t] = s; __syncthreads();
    for (int o = 128; o; o >>= 1) { if (t < o) sm[t] += sm[t + o]; __syncthreads(); }
    if (!t) part[b] = sm[0];
}

// ---------------- scan phase 2: exclusive scan of 256 partials (in place) ----------------
__global__ __launch_bounds__(256) void k_scan_top(int* __restrict__ part) {
    int t = threadIdx.x;
    __shared__ int sm[256];
    int v = part[t];
    sm[t] = v; __syncthreads();
    for (int o = 1; o < 256; o <<= 1) {
        int u = (t >= o) ? sm[t - o] : 0;
        __syncthreads();
        sm[t] += u;
        __syncthreads();
    }
    part[t] = sm[t] - v;
}

// ---------------- scan phase 3: offsets + norms ----------------
__global__ __launch_bounds__(256) void k_scan_fill(const int* __restrict__ ind,
                                                   const int* __restrict__ outd,
                                                   const int* __restrict__ part,
                                                   int* __restrict__ offs,
                                                   float* __restrict__ ns,
                                                   float* __restrict__ nd, int N) {
    int b = blockIdx.x, t = threadIdx.x;
    int CH = (N + 255) / 256;
    int lo = b * CH, hi = min(N, lo + CH);
    __shared__ int sm[256];
    int base = part[b];
    for (int s0 = lo; s0 < hi; s0 += 256) {
        int i = s0 + t;
        int v = (i < hi) ? ind[i] : 0;
        sm[t] = v; __syncthreads();
        for (int o = 1; o < 256; o <<= 1) {
            int u = (t >= o) ? sm[t - o] : 0;
            __syncthreads();
            sm[t] += u;
            __syncthreads();
        }
        if (i < hi) {
            offs[i] = base + sm[t] - v;
            int od = outd[i];
            ns[i] = od > 0 ? rsqrtf((float)od) : 0.f;
            nd[i] = v > 0 ? rsqrtf((float)v) : 0.f;
        }
        base += sm[255];
        __syncthreads();
    }
    if (b == 255 && t == 0) offs[N] = base;
}

// ---------------- CSR fill (atomic-free) ----------------
__global__ void k_fill(const int* __restrict__ src, const int* __restrict__ dst,
                       const int* __restrict__ rank, const int* __restrict__ offs,
                       int* __restrict__ csr, int E) {
    int tid = blockIdx.x * blockDim.x + threadIdx.x;
    int stride = gridDim.x * blockDim.x;
    int E4 = E >> 2;
    const int4* src4 = (const int4*)src;
    const int4* dst4 = (const int4*)dst;
    const int4* rank4 = (const int4*)rank;
    for (int i = tid; i < E4; i += stride) {
        int4 s = src4[i], d = dst4[i], r = rank4[i];
        csr[offs[d.x] + r.x] = s.x;
        csr[offs[d.y] + r.y] = s.y;
        csr[offs[d.z] + r.z] = s.z;
        csr[offs[d.w] + r.w] = s.w;
    }
    for (int i = E4 * 4 + tid; i < E; i += stride)
        csr[offs[dst[i]] + rank[i]] = src[i];
}

// ---------------- GEMM: C[M,256] = A[M,256] @ B[256,256], rows scaled by ns ----------------
// 128x128 block tile, 256 threads, 8x8 per thread (split 4+4 to kill LDS read conflicts).
__global__ __launch_bounds__(256) void k_gemm(const float* __restrict__ A,
                                              const float* __restrict__ B,
                                              const float* __restrict__ ns,
                                              float* __restrict__ C, int M) {
    __shared__ float As[16][132];   // As[k][m]
    __shared__ float Bs[16][132];   // Bs[k][n]
    int t = threadIdx.x;
    int tx = t & 15, ty = t >> 4;
    int row0 = blockIdx.x * 128;
    int col0 = blockIdx.y * 128;
    float c[8][8] = {};
    for (int k0 = 0; k0 < 256; k0 += 16) {
        {
            int ar = t >> 1;
            int ak = (t & 1) * 8;
            int grow = row0 + ar;
            float4 a0 = make_float4(0.f, 0.f, 0.f, 0.f), a1 = a0;
            if (grow < M) {
                a0 = *(const float4*)&A[(size_t)grow * 256 + k0 + ak];
                a1 = *(const float4*)&A[(size_t)grow * 256 + k0 + ak + 4];
            }
            As[ak + 0][ar] = a0.x; As[ak + 1][ar] = a0.y;
            As[ak + 2][ar] = a0.z; As[ak + 3][ar] = a0.w;
            As[ak + 4][ar] = a1.x; As[ak + 5][ar] = a1.y;
            As[ak + 6][ar] = a1.z; As[ak + 7][ar] = a1.w;
        }
        {
            int br = t >> 4;
            int bc = (t & 15) * 8;
            float4 b0 = *(const float4*)&B[(size_t)(k0 + br) * 256 + col0 + bc];
            float4 b1 = *(const float4*)&B[(size_t)(k0 + br) * 256 + col0 + bc + 4];
            *(float4*)&Bs[br][bc] = b0;
            *(float4*)&Bs[br][bc + 4] = b1;
        }
        __syncthreads();
#pragma unroll
        for (int k = 0; k < 16; ++k) {
            float a[8], b[8];
            *(float4*)&a[0] = *(float4*)&As[k][ty * 4];
            *(float4*)&a[4] = *(float4*)&As[k][64 + ty * 4];
            *(float4*)&b[0] = *(float4*)&Bs[k][tx * 4];
            *(float4*)&b[4] = *(float4*)&Bs[k][64 + tx * 4];
#pragma unroll
            for (int i = 0; i < 8; ++i)
#pragma unroll
                for (int j = 0; j < 8; ++j)
                    c[i][j] = fmaf(a[i], b[j], c[i][j]);
        }
        __syncthreads();
    }
#pragma unroll
    for (int i = 0; i < 8; ++i) {
        int grow = row0 + ((i < 4) ? (ty * 4 + i) : (64 + ty * 4 + i - 4));
        if (grow < M) {
            float s = ns[grow];
            float4 v0 = make_float4(c[i][0] * s, c[i][1] * s, c[i][2] * s, c[i][3] * s);
            float4 v1 = make_float4(c[i][4] * s, c[i][5] * s, c[i][6] * s, c[i][7] * s);
            *(float4*)&C[(size_t)grow * 256 + col0 + tx * 4] = v0;
            *(float4*)&C[(size_t)grow * 256 + col0 + 64 + tx * 4] = v1;
        }
    }
}

// ---------------- aggregate (column-half pass): out[n, c0:c0+128] ----------------
__global__ __launch_bounds__(256) void k_agg_half(const float* __restrict__ h,
                                                  const int* __restrict__ csr,
                                                  const int* __restrict__ offs,
                                                  const float* __restrict__ nd,
                                                  const float* __restrict__ bias,
                                                  float* __restrict__ out, int N, int c0) {
    int wave = threadIdx.x >> 6;
    int lane = threadIdx.x & 63;
    int half = lane >> 5;
    int l = lane & 31;
    int node = blockIdx.x * 8 + wave * 2 + half;
    if (node >= N) return;
    int e0 = offs[node], e1 = offs[node + 1];
    int c = c0 + l * 4;
    float4 acc = make_float4(0.f, 0.f, 0.f, 0.f);
    for (int e = e0; e < e1; ++e) {
        int s = csr[e];
        float4 v = *(const float4*)&h[(size_t)s * 256 + c];
        acc.x += v.x; acc.y += v.y; acc.z += v.z; acc.w += v.w;
    }
    float sc = nd[node];
    float4 b = *(const float4*)&bias[c];
    float4 r;
    r.x = fmaxf(fmaf(acc.x, sc, b.x), 0.f);
    r.y = fmaxf(fmaf(acc.y, sc, b.y), 0.f);
    r.z = fmaxf(fmaf(acc.z, sc, b.z), 0.f);
    r.w = fmaxf(fmaf(acc.w, sc, b.w), 0.f);
    *(float4*)&out[(size_t)node * 256 + c] = r;
}

// ---------------- pool + linear + log_softmax ----------------
__global__ __launch_bounds__(256) void k_pool(const float* __restrict__ h,
                                              const int* __restrict__ gid,
                                              const float* __restrict__ Wlin,
                                              const float* __restrict__ blin,
                                              float* __restrict__ out, int N) {
    int g = blockIdx.x;
    int t = threadIdx.x;
    int s, e;
    {
        int lo = 0, hi = N;
        while (lo < hi) { int m = (lo + hi) >> 1; if (gid[m] < g) lo = m + 1; else hi = m; }
        s = lo;
        lo = s; hi = N;
        while (lo < hi) { int m = (lo + hi) >> 1; if (gid[m] < g + 1) lo = m + 1; else hi = m; }
        e = lo;
    }
    float acc = 0.f;
    for (int i = s; i < e; ++i) acc += h[(size_t)i * 256 + t];
    float cntf = (float)((e - s) > 0 ? (e - s) : 1);
    __shared__ float hg[256];
    hg[t] = acc / cntf;
    __syncthreads();
    if (t < 16) {
        float v = blin[t];
        for (int k = 0; k < 256; ++k) v = fmaf(hg[k], Wlin[k * 16 + t], v);
        float m = v;
#pragma unroll
        for (int off = 8; off; off >>= 1) m = fmaxf(m, __shfl_xor(m, off, 16));
        float ex = expf(v - m);
        float ssum = ex;
#pragma unroll
        for (int off = 8; off; off >>= 1) ssum += __shfl_xor(ssum, off, 16);
        out[g * 16 + t] = v - m - logf(ssum);
    }
}

extern "C" void kernel_launch(void* const* d_in, const int* in_sizes, int n_in,
                              void* d_out, int out_size, void* d_ws, size_t ws_size,
                              hipStream_t stream) {
    const float* feats   = (const float*)d_in[0];
    const int*   edge_src= (const int*)d_in[1];
    const int*   edge_dst= (const int*)d_in[2];
    const int*   gid     = (const int*)d_in[3];
    const float* W1 = (const float*)d_in[4];  const float* b1 = (const float*)d_in[5];
    const float* W2 = (const float*)d_in[6];  const float* b2 = (const float*)d_in[7];
    const float* W3 = (const float*)d_in[8];  const float* b3 = (const float*)d_in[9];
    const float* Wlin = (const float*)d_in[10]; const float* blin = (const float*)d_in[11];
    float* out = (float*)d_out;

    const int E = in_sizes[1];
    const int N = in_sizes[3];
    const int G = 256;

    size_t off = 0;
    auto alloc = [&](size_t bytes) -> void* {
        void* p = (char*)d_ws + off;
        off += (bytes + 255) & ~(size_t)255;
        return p;
    };
    int*   outd = (int*)alloc((size_t)N * 4);
    int*   ind  = (int*)alloc((size_t)N * 4);
    size_t zero_bytes = off;                    // zero the two atomic-counter arrays
    int*   part = (int*)alloc(256 * 4);
    int*   offs = (int*)alloc(((size_t)N + 1) * 4);
    float* ns   = (float*)alloc((size_t)N * 4);
    float* nd   = (float*)alloc((size_t)N * 4);
    int*   csr  = (int*)alloc((size_t)E * 4);
    float* htmp = (float*)alloc((size_t)N * HID * 4);
    float* buf  = (float*)alloc((size_t)N * HID * 4);
    // rank aliased onto buf: consumed by k_fill before buf's first write (layer-1 agg)
    int*   rank = (int*)buf;
    (void)ws_size;

    hipMemsetAsync(d_ws, 0, zero_bytes, stream);

    k_degree_rank<<<2048, 256, 0, stream>>>(edge_src, edge_dst, outd, ind, rank, E);
    k_scan_part<<<256, 256, 0, stream>>>(ind, part, N);
    k_scan_top<<<1, 256, 0, stream>>>(part);
    k_scan_fill<<<256, 256, 0, stream>>>(ind, outd, part, offs, ns, nd, N);
    k_fill<<<2048, 256, 0, stream>>>(edge_src, edge_dst, rank, offs, csr, E);

    dim3 ggrid((N + 127) / 128, 2);
    int agg_blocks = (N + 7) / 8;

    // layer 1
    k_gemm<<<ggrid, 256, 0, stream>>>(feats, W1, ns, htmp, N);
    k_agg_half<<<agg_blocks, 256, 0, stream>>>(htmp, csr, offs, nd, b1, buf, N, 0);
    k_agg_half<<<agg_blocks, 256, 0, stream>>>(htmp, csr, offs, nd, b1, buf, N, 128);
    // layer 2
    k_gemm<<<ggrid, 256, 0, stream>>>(buf, W2, ns, htmp, N);
    k_agg_half<<<agg_blocks, 256, 0, stream>>>(htmp, csr, offs, nd, b2, buf, N, 0);
    k_agg_half<<<agg_blocks, 256, 0, stream>>>(htmp, csr, offs, nd, b2, buf, N, 128);
    // layer 3
    k_gemm<<<ggrid, 256, 0, stream>>>(buf, W3, ns, htmp, N);
    k_agg_half<<<agg_blocks, 256, 0, stream>>>(htmp, csr, offs, nd, b3, buf, N, 0);
    k_agg_half<<<agg_blocks, 256, 0, stream>>>(htmp, csr, offs, nd, b3, buf, N, 128);

    k_pool<<<G, 256, 0, stream>>>(buf, gid, Wlin, blin, out, N);
    (void)out_size;
}

// Round 7
// 1770.535 us; speedup vs baseline: 1.5393x; 1.3773x over previous
//
#include <hip/hip_runtime.h>
#include <math.h>

// GCN: 3x (X@W -> scale by norm_src -> gather-sum over in-edges -> *norm_dst + b -> relu)
// then mean-pool per graph, linear to 16 classes, log_softmax.
// h = X@W stored as bf16 (halves gather traffic; 51MB working set is L3-resident).

#define HID 256

static __device__ __forceinline__ unsigned short f2bf(float f) {
    unsigned int u = __float_as_uint(f);
    unsigned int r = (u + 0x7fff + ((u >> 16) & 1)) >> 16;   // RNE
    return (unsigned short)r;
}
static __device__ __forceinline__ float bf2f(unsigned short v) {
    return __uint_as_float(((unsigned int)v) << 16);
}

// ---------------- degree + rank (rank = in-edge slot via atomic return) ----------------
__global__ void k_degree_rank(const int* __restrict__ src, const int* __restrict__ dst,
                              int* __restrict__ outd, int* __restrict__ ind,
                              int* __restrict__ rank, int E) {
    int tid = blockIdx.x * blockDim.x + threadIdx.x;
    int stride = gridDim.x * blockDim.x;
    int E4 = E >> 2;
    const int4* src4 = (const int4*)src;
    const int4* dst4 = (const int4*)dst;
    int4* rank4 = (int4*)rank;
    for (int i = tid; i < E4; i += stride) {
        int4 s = src4[i], d = dst4[i];
        atomicAdd(&outd[s.x], 1); atomicAdd(&outd[s.y], 1);
        atomicAdd(&outd[s.z], 1); atomicAdd(&outd[s.w], 1);
        int4 r;
        r.x = atomicAdd(&ind[d.x], 1);
        r.y = atomicAdd(&ind[d.y], 1);
        r.z = atomicAdd(&ind[d.z], 1);
        r.w = atomicAdd(&ind[d.w], 1);
        rank4[i] = r;
    }
    for (int i = E4 * 4 + tid; i < E; i += stride) {
        atomicAdd(&outd[src[i]], 1);
        rank[i] = atomicAdd(&ind[dst[i]], 1);
    }
}

// ---------------- scan phase 1: per-block partial sums of in-degree ----------------
__global__ __launch_bounds__(256) void k_scan_part(const int* __restrict__ ind,
                                                   int* __restrict__ part, int N) {
    int b = blockIdx.x, t = threadIdx.x;
    int CH = (N + 255) / 256;
    int lo = b * CH, hi = min(N, lo + CH);
    int s = 0;
    for (int i = lo + t; i < hi; i += 256) s += ind[i];
    __shared__ int sm[256];
    sm[t] = s; __syncthreads();
    for (int o = 128; o; o >>= 1) { if (t < o) sm[t] += sm[t + o]; __syncthreads(); }
    if (!t) part[b] = sm[0];
}

// ---------------- scan phase 2: exclusive scan of 256 partials (in place) ----------------
__global__ __launch_bounds__(256) void k_scan_top(int* __restrict__ part) {
    int t = threadIdx.x;
    __shared__ int sm[256];
    int v = part[t];
    sm[t] = v; __syncthreads();
    for (int o = 1; o < 256; o <<= 1) {
        int u = (t >= o) ? sm[t - o] : 0;
        __syncthreads();
        sm[t] += u;
        __syncthreads();
    }
    part[t] = sm[t] - v;
}

// ---------------- scan phase 3: offsets + norms ----------------
__global__ __launch_bounds__(256) void k_scan_fill(const int* __restrict__ ind,
                                                   const int* __restrict__ outd,
                                                   const int* __restrict__ part,
                                                   int* __restrict__ offs,
                                                   float* __restrict__ ns,
                                                   float* __restrict__ nd, int N) {
    int b = blockIdx.x, t = threadIdx.x;
    int CH = (N + 255) / 256;
    int lo = b * CH, hi = min(N, lo + CH);
    __shared__ int sm[256];
    int base = part[b];
    for (int s0 = lo; s0 < hi; s0 += 256) {
        int i = s0 + t;
        int v = (i < hi) ? ind[i] : 0;
        sm[t] = v; __syncthreads();
        for (int o = 1; o < 256; o <<= 1) {
            int u = (t >= o) ? sm[t - o] : 0;
            __syncthreads();
            sm[t] += u;
            __syncthreads();
        }
        if (i < hi) {
            offs[i] = base + sm[t] - v;
            int od = outd[i];
            ns[i] = od > 0 ? rsqrtf((float)od) : 0.f;
            nd[i] = v > 0 ? rsqrtf((float)v) : 0.f;
        }
        base += sm[255];
        __syncthreads();
    }
    if (b == 255 && t == 0) offs[N] = base;
}

// ---------------- CSR fill (atomic-free) ----------------
__global__ void k_fill(const int* __restrict__ src, const int* __restrict__ dst,
                       const int* __restrict__ rank, const int* __restrict__ offs,
                       int* __restrict__ csr, int E) {
    int tid = blockIdx.x * blockDim.x + threadIdx.x;
    int stride = gridDim.x * blockDim.x;
    int E4 = E >> 2;
    const int4* src4 = (const int4*)src;
    const int4* dst4 = (const int4*)dst;
    const int4* rank4 = (const int4*)rank;
    for (int i = tid; i < E4; i += stride) {
        int4 s = src4[i], d = dst4[i], r = rank4[i];
        csr[offs[d.x] + r.x] = s.x;
        csr[offs[d.y] + r.y] = s.y;
        csr[offs[d.z] + r.z] = s.z;
        csr[offs[d.w] + r.w] = s.w;
    }
    for (int i = E4 * 4 + tid; i < E; i += stride)
        csr[offs[dst[i]] + rank[i]] = src[i];
}

// ---------------- GEMM: C_bf16[M,256] = (A[M,256] @ B[256,256]) * ns[row] ----------------
// 128x128 block tile, 256 threads, 8x8 per thread.
__global__ __launch_bounds__(256) void k_gemm(const float* __restrict__ A,
                                              const float* __restrict__ B,
                                              const float* __restrict__ ns,
                                              unsigned short* __restrict__ C, int M) {
    __shared__ float As[16][132];   // As[k][m]
    __shared__ float Bs[16][132];   // Bs[k][n]
    int t = threadIdx.x;
    int tx = t & 15, ty = t >> 4;
    int row0 = blockIdx.x * 128;
    int col0 = blockIdx.y * 128;
    float c[8][8] = {};
    for (int k0 = 0; k0 < 256; k0 += 16) {
        {
            int ar = t >> 1;
            int ak = (t & 1) * 8;
            int grow = row0 + ar;
            float4 a0 = make_float4(0.f, 0.f, 0.f, 0.f), a1 = a0;
            if (grow < M) {
                a0 = *(const float4*)&A[(size_t)grow * 256 + k0 + ak];
                a1 = *(const float4*)&A[(size_t)grow * 256 + k0 + ak + 4];
            }
            As[ak + 0][ar] = a0.x; As[ak + 1][ar] = a0.y;
            As[ak + 2][ar] = a0.z; As[ak + 3][ar] = a0.w;
            As[ak + 4][ar] = a1.x; As[ak + 5][ar] = a1.y;
            As[ak + 6][ar] = a1.z; As[ak + 7][ar] = a1.w;
        }
        {
            int br = t >> 4;
            int bc = (t & 15) * 8;
            float4 b0 = *(const float4*)&B[(size_t)(k0 + br) * 256 + col0 + bc];
            float4 b1 = *(const float4*)&B[(size_t)(k0 + br) * 256 + col0 + bc + 4];
            *(float4*)&Bs[br][bc] = b0;
            *(float4*)&Bs[br][bc + 4] = b1;
        }
        __syncthreads();
#pragma unroll
        for (int k = 0; k < 16; ++k) {
            float a[8], b[8];
            *(float4*)&a[0] = *(float4*)&As[k][ty * 4];
            *(float4*)&a[4] = *(float4*)&As[k][64 + ty * 4];
            *(float4*)&b[0] = *(float4*)&Bs[k][tx * 4];
            *(float4*)&b[4] = *(float4*)&Bs[k][64 + tx * 4];
#pragma unroll
            for (int i = 0; i < 8; ++i)
#pragma unroll
                for (int j = 0; j < 8; ++j)
                    c[i][j] = fmaf(a[i], b[j], c[i][j]);
        }
        __syncthreads();
    }
#pragma unroll
    for (int i = 0; i < 8; ++i) {
        int grow = row0 + ((i < 4) ? (ty * 4 + i) : (64 + ty * 4 + i - 4));
        if (grow < M) {
            float s = ns[grow];
            ushort4 v0, v1;
            v0.x = f2bf(c[i][0] * s); v0.y = f2bf(c[i][1] * s);
            v0.z = f2bf(c[i][2] * s); v0.w = f2bf(c[i][3] * s);
            v1.x = f2bf(c[i][4] * s); v1.y = f2bf(c[i][5] * s);
            v1.z = f2bf(c[i][6] * s); v1.w = f2bf(c[i][7] * s);
            *(ushort4*)&C[(size_t)grow * 256 + col0 + tx * 4] = v0;
            *(ushort4*)&C[(size_t)grow * 256 + col0 + 64 + tx * 4] = v1;
        }
    }
}

// ---------------- aggregate: out[n,:] = relu(nd[n] * sum_e h_bf16[src(e),:] + b) ----------------
// One wave per node: 64 lanes x 4 bf16 cols = 256 cols, 512B coalesced per edge.
__global__ __launch_bounds__(256) void k_agg(const unsigned short* __restrict__ h,
                                             const int* __restrict__ csr,
                                             const int* __restrict__ offs,
                                             const float* __restrict__ nd,
                                             const float* __restrict__ bias,
                                             float* __restrict__ out, int N) {
    int wave = threadIdx.x >> 6;
    int lane = threadIdx.x & 63;
    int node = blockIdx.x * 4 + wave;
    if (node >= N) return;
    int e0 = offs[node], e1 = offs[node + 1];
    float acc0 = 0.f, acc1 = 0.f, acc2 = 0.f, acc3 = 0.f;
    int e = e0;
    for (; e + 1 < e1; e += 2) {
        int s0 = csr[e], s1 = csr[e + 1];
        ushort4 a = *(const ushort4*)&h[(size_t)s0 * 256 + lane * 4];
        ushort4 b = *(const ushort4*)&h[(size_t)s1 * 256 + lane * 4];
        acc0 += bf2f(a.x); acc1 += bf2f(a.y); acc2 += bf2f(a.z); acc3 += bf2f(a.w);
        acc0 += bf2f(b.x); acc1 += bf2f(b.y); acc2 += bf2f(b.z); acc3 += bf2f(b.w);
    }
    if (e < e1) {
        int s0 = csr[e];
        ushort4 a = *(const ushort4*)&h[(size_t)s0 * 256 + lane * 4];
        acc0 += bf2f(a.x); acc1 += bf2f(a.y); acc2 += bf2f(a.z); acc3 += bf2f(a.w);
    }
    float sc = nd[node];
    float4 b4 = *(const float4*)&bias[lane * 4];
    float4 r;
    r.x = fmaxf(fmaf(acc0, sc, b4.x), 0.f);
    r.y = fmaxf(fmaf(acc1, sc, b4.y), 0.f);
    r.z = fmaxf(fmaf(acc2, sc, b4.z), 0.f);
    r.w = fmaxf(fmaf(acc3, sc, b4.w), 0.f);
    *(float4*)&out[(size_t)node * 256 + lane * 4] = r;
}

// ---------------- pool + linear + log_softmax ----------------
__global__ __launch_bounds__(256) void k_pool(const float* __restrict__ h,
                                              const int* __restrict__ gid,
                                              const float* __restrict__ Wlin,
                                              const float* __restrict__ blin,
                                              float* __restrict__ out, int N) {
    int g = blockIdx.x;
    int t = threadIdx.x;
    int s, e;
    {
        int lo = 0, hi = N;
        while (lo < hi) { int m = (lo + hi) >> 1; if (gid[m] < g) lo = m + 1; else hi = m; }
        s = lo;
        lo = s; hi = N;
        while (lo < hi) { int m = (lo + hi) >> 1; if (gid[m] < g + 1) lo = m + 1; else hi = m; }
        e = lo;
    }
    float acc = 0.f;
    for (int i = s; i < e; ++i) acc += h[(size_t)i * 256 + t];
    float cntf = (float)((e - s) > 0 ? (e - s) : 1);
    __shared__ float hg[256];
    hg[t] = acc / cntf;
    __syncthreads();
    if (t < 16) {
        float v = blin[t];
        for (int k = 0; k < 256; ++k) v = fmaf(hg[k], Wlin[k * 16 + t], v);
        float m = v;
#pragma unroll
        for (int off = 8; off; off >>= 1) m = fmaxf(m, __shfl_xor(m, off, 16));
        float ex = expf(v - m);
        float ssum = ex;
#pragma unroll
        for (int off = 8; off; off >>= 1) ssum += __shfl_xor(ssum, off, 16);
        out[g * 16 + t] = v - m - logf(ssum);
    }
}

extern "C" void kernel_launch(void* const* d_in, const int* in_sizes, int n_in,
                              void* d_out, int out_size, void* d_ws, size_t ws_size,
                              hipStream_t stream) {
    const float* feats   = (const float*)d_in[0];
    const int*   edge_src= (const int*)d_in[1];
    const int*   edge_dst= (const int*)d_in[2];
    const int*   gid     = (const int*)d_in[3];
    const float* W1 = (const float*)d_in[4];  const float* b1 = (const float*)d_in[5];
    const float* W2 = (const float*)d_in[6];  const float* b2 = (const float*)d_in[7];
    const float* W3 = (const float*)d_in[8];  const float* b3 = (const float*)d_in[9];
    const float* Wlin = (const float*)d_in[10]; const float* blin = (const float*)d_in[11];
    float* out = (float*)d_out;

    const int E = in_sizes[1];
    const int N = in_sizes[3];
    const int G = 256;

    size_t off = 0;
    auto alloc = [&](size_t bytes) -> void* {
        void* p = (char*)d_ws + off;
        off += (bytes + 255) & ~(size_t)255;
        return p;
    };
    int*   outd = (int*)alloc((size_t)N * 4);
    int*   ind  = (int*)alloc((size_t)N * 4);
    size_t zero_bytes = off;                    // zero the two atomic-counter arrays
    int*   part = (int*)alloc(256 * 4);
    int*   offs = (int*)alloc(((size_t)N + 1) * 4);
    float* ns   = (float*)alloc((size_t)N * 4);
    float* nd   = (float*)alloc((size_t)N * 4);
    int*   csr  = (int*)alloc((size_t)E * 4);
    unsigned short* htmp = (unsigned short*)alloc((size_t)N * HID * 2);  // bf16
    float* buf  = (float*)alloc((size_t)N * HID * 4);
    // rank aliased onto buf: consumed by k_fill before buf's first write (layer-1 agg)
    int*   rank = (int*)buf;
    (void)ws_size;

    hipMemsetAsync(d_ws, 0, zero_bytes, stream);

    k_degree_rank<<<2048, 256, 0, stream>>>(edge_src, edge_dst, outd, ind, rank, E);
    k_scan_part<<<256, 256, 0, stream>>>(ind, part, N);
    k_scan_top<<<1, 256, 0, stream>>>(part);
    k_scan_fill<<<256, 256, 0, stream>>>(ind, outd, part, offs, ns, nd, N);
    k_fill<<<2048, 256, 0, stream>>>(edge_src, edge_dst, rank, offs, csr, E);

    dim3 ggrid((N + 127) / 128, 2);
    int agg_blocks = (N + 3) / 4;

    // layer 1
    k_gemm<<<ggrid, 256, 0, stream>>>(feats, W1, ns, htmp, N);
    k_agg<<<agg_blocks, 256, 0, stream>>>(htmp, csr, offs, nd, b1, buf, N);
    // layer 2
    k_gemm<<<ggrid, 256, 0, stream>>>(buf, W2, ns, htmp, N);
    k_agg<<<agg_blocks, 256, 0, stream>>>(htmp, csr, offs, nd, b2, buf, N);
    // layer 3
    k_gemm<<<ggrid, 256, 0, stream>>>(buf, W3, ns, htmp, N);
    k_agg<<<agg_blocks, 256, 0, stream>>>(htmp, csr, offs, nd, b3, buf, N);

    k_pool<<<G, 256, 0, stream>>>(buf, gid, Wlin, blin, out, N);
    (void)out_size;
}

// Round 9
// 1467.693 us; speedup vs baseline: 1.8569x; 1.2063x over previous
//
#include <hip/hip_runtime.h>
#include <math.h>

// GCN: 3x (X@W -> scale by norm_src -> gather-sum over in-edges -> *norm_dst + b -> relu)
// then mean-pool per graph, linear to 16 classes, log_softmax.
// All hidden activations in bf16; GEMMs via MFMA 16x16x32 bf16.

#define HID 256

typedef __attribute__((ext_vector_type(4))) short short4v;
typedef __attribute__((ext_vector_type(8))) short short8v;
typedef __attribute__((ext_vector_type(4))) float f32x4;

static __device__ __forceinline__ unsigned short f2bf(float f) {
    unsigned int u = __float_as_uint(f);
    unsigned int r = (u + 0x7fff + ((u >> 16) & 1)) >> 16;   // RNE
    return (unsigned short)r;
}
static __device__ __forceinline__ float bf2f(unsigned short v) {
    return __uint_as_float(((unsigned int)v) << 16);
}

// ---------------- degree + rank (rank = in-edge slot via atomic return) ----------------
__global__ void k_degree_rank(const int* __restrict__ src, const int* __restrict__ dst,
                              int* __restrict__ outd, int* __restrict__ ind,
                              int* __restrict__ rank, int E) {
    int tid = blockIdx.x * blockDim.x + threadIdx.x;
    int stride = gridDim.x * blockDim.x;
    int E4 = E >> 2;
    const int4* src4 = (const int4*)src;
    const int4* dst4 = (const int4*)dst;
    int4* rank4 = (int4*)rank;
    for (int i = tid; i < E4; i += stride) {
        int4 s = src4[i], d = dst4[i];
        atomicAdd(&outd[s.x], 1); atomicAdd(&outd[s.y], 1);
        atomicAdd(&outd[s.z], 1); atomicAdd(&outd[s.w], 1);
        int4 r;
        r.x = atomicAdd(&ind[d.x], 1);
        r.y = atomicAdd(&ind[d.y], 1);
        r.z = atomicAdd(&ind[d.z], 1);
        r.w = atomicAdd(&ind[d.w], 1);
        rank4[i] = r;
    }
    for (int i = E4 * 4 + tid; i < E; i += stride) {
        atomicAdd(&outd[src[i]], 1);
        rank[i] = atomicAdd(&ind[dst[i]], 1);
    }
}

// ---------------- scan phase 1 ----------------
__global__ __launch_bounds__(256) void k_scan_part(const int* __restrict__ ind,
                                                   int* __restrict__ part, int N) {
    int b = blockIdx.x, t = threadIdx.x;
    int CH = (N + 255) / 256;
    int lo = b * CH, hi = min(N, lo + CH);
    int s = 0;
    for (int i = lo + t; i < hi; i += 256) s += ind[i];
    __shared__ int sm[256];
    sm[t] = s; __syncthreads();
    for (int o = 128; o; o >>= 1) { if (t < o) sm[t] += sm[t + o]; __syncthreads(); }
    if (!t) part[b] = sm[0];
}

// ---------------- scan phase 2 ----------------
__global__ __launch_bounds__(256) void k_scan_top(int* __restrict__ part) {
    int t = threadIdx.x;
    __shared__ int sm[256];
    int v = part[t];
    sm[t] = v; __syncthreads();
    for (int o = 1; o < 256; o <<= 1) {
        int u = (t >= o) ? sm[t - o] : 0;
        __syncthreads();
        sm[t] += u;
        __syncthreads();
    }
    part[t] = sm[t] - v;
}

// ---------------- scan phase 3: offsets + norms ----------------
__global__ __launch_bounds__(256) void k_scan_fill(const int* __restrict__ ind,
                                                   const int* __restrict__ outd,
                                                   const int* __restrict__ part,
                                                   int* __restrict__ offs,
                                                   float* __restrict__ ns,
                                                   float* __restrict__ nd, int N) {
    int b = blockIdx.x, t = threadIdx.x;
    int CH = (N + 255) / 256;
    int lo = b * CH, hi = min(N, lo + CH);
    __shared__ int sm[256];
    int base = part[b];
    for (int s0 = lo; s0 < hi; s0 += 256) {
        int i = s0 + t;
        int v = (i < hi) ? ind[i] : 0;
        sm[t] = v; __syncthreads();
        for (int o = 1; o < 256; o <<= 1) {
            int u = (t >= o) ? sm[t - o] : 0;
            __syncthreads();
            sm[t] += u;
            __syncthreads();
        }
        if (i < hi) {
            offs[i] = base + sm[t] - v;
            int od = outd[i];
            ns[i] = od > 0 ? rsqrtf((float)od) : 0.f;
            nd[i] = v > 0 ? rsqrtf((float)v) : 0.f;
        }
        base += sm[255];
        __syncthreads();
    }
    if (b == 255 && t == 0) offs[N] = base;
}

// ---------------- CSR fill (atomic-free) ----------------
__global__ void k_fill(const int* __restrict__ src, const int* __restrict__ dst,
                       const int* __restrict__ rank, const int* __restrict__ offs,
                       int* __restrict__ csr, int E) {
    int tid = blockIdx.x * blockDim.x + threadIdx.x;
    int stride = gridDim.x * blockDim.x;
    int E4 = E >> 2;
    const int4* src4 = (const int4*)src;
    const int4* dst4 = (const int4*)dst;
    const int4* rank4 = (const int4*)rank;
    for (int i = tid; i < E4; i += stride) {
        int4 s = src4[i], d = dst4[i], r = rank4[i];
        csr[offs[d.x] + r.x] = s.x;
        csr[offs[d.y] + r.y] = s.y;
        csr[offs[d.z] + r.z] = s.z;
        csr[offs[d.w] + r.w] = s.w;
    }
    for (int i = E4 * 4 + tid; i < E; i += stride)
        csr[offs[dst[i]] + rank[i]] = src[i];
}

// ---------------- cast feats fp32 -> bf16 ----------------
__global__ void k_cast(const float* __restrict__ in, unsigned short* __restrict__ out, int n4) {
    int i = blockIdx.x * blockDim.x + threadIdx.x;
    int stride = gridDim.x * blockDim.x;
    for (; i < n4; i += stride) {
        float4 v = ((const float4*)in)[i];
        ushort4 o;
        o.x = f2bf(v.x); o.y = f2bf(v.y); o.z = f2bf(v.z); o.w = f2bf(v.w);
        ((ushort4*)out)[i] = o;
    }
}

// ---------------- W -> Wt bf16 transposed (Wt[n][k] = W[k][n]), 3 matrices ----------------
__global__ __launch_bounds__(256) void k_wprep(const float* __restrict__ W1,
                                               const float* __restrict__ W2,
                                               const float* __restrict__ W3,
                                               unsigned short* __restrict__ Wt) {
    int n = blockIdx.x, t = threadIdx.x;
    Wt[0 * 65536 + n * 256 + t] = f2bf(W1[t * 256 + n]);
    Wt[1 * 65536 + n * 256 + t] = f2bf(W2[t * 256 + n]);
    Wt[2 * 65536 + n * 256 + t] = f2bf(W3[t * 256 + n]);
}

// ---------------- MFMA GEMM: C_bf16[M,256] = (A_bf16[M,256] @ W) * ns[row] ----------------
// Bt[n][k] = W[k][n] bf16. 128x128 tile, 4 waves (2x2), wave-tile 64x64 = 4x4 frags 16x16.
__global__ __launch_bounds__(256) void k_gemm_mf(const unsigned short* __restrict__ A,
                                                 const unsigned short* __restrict__ Bt,
                                                 const float* __restrict__ ns,
                                                 unsigned short* __restrict__ C, int M) {
    __shared__ unsigned short As[128 * 40];   // [row][k] padded 32->40
    __shared__ unsigned short Bs[128 * 40];   // [col][k] padded
    int t = threadIdx.x;
    int m0 = blockIdx.x * 128, n0 = blockIdx.y * 128;
    int w = t >> 6, lane = t & 63;
    int wr = w >> 1, wc = w & 1;
    int l15 = lane & 15, l4 = lane >> 4;      // l4 in 0..3
    f32x4 acc[4][4] = {};
    for (int k0 = 0; k0 < 256; k0 += 32) {
#pragma unroll
        for (int j = 0; j < 2; ++j) {
            int chunk = t + 256 * j;          // 0..511
            int r = chunk >> 2, q = chunk & 3;
            int grow = m0 + r;
            ushort4 v0 = {0, 0, 0, 0}, v1 = {0, 0, 0, 0};
            if (grow < M) {
                v0 = *(const ushort4*)&A[(size_t)grow * 256 + k0 + q * 8];
                v1 = *(const ushort4*)&A[(size_t)grow * 256 + k0 + q * 8 + 4];
            }
            *(ushort4*)&As[r * 40 + q * 8] = v0;
            *(ushort4*)&As[r * 40 + q * 8 + 4] = v1;
            ushort4 u0 = *(const ushort4*)&Bt[(size_t)(n0 + r) * 256 + k0 + q * 8];
            ushort4 u1 = *(const ushort4*)&Bt[(size_t)(n0 + r) * 256 + k0 + q * 8 + 4];
            *(ushort4*)&Bs[r * 40 + q * 8] = u0;
            *(ushort4*)&Bs[r * 40 + q * 8 + 4] = u1;
        }
        __syncthreads();
        short8v af[4], bf[4];
#pragma unroll
        for (int f = 0; f < 4; ++f) {
            int ar = wr * 64 + f * 16 + l15;
            short4v lo = *(const short4v*)&As[ar * 40 + l4 * 4];
            short4v hi = *(const short4v*)&As[ar * 40 + l4 * 4 + 16];
            af[f] = __builtin_shufflevector(lo, hi, 0, 1, 2, 3, 4, 5, 6, 7);
            int bc = wc * 64 + f * 16 + l15;
            short4v blo = *(const short4v*)&Bs[bc * 40 + l4 * 4];
            short4v bhi = *(const short4v*)&Bs[bc * 40 + l4 * 4 + 16];
            bf[f] = __builtin_shufflevector(blo, bhi, 0, 1, 2, 3, 4, 5, 6, 7);
        }
#pragma unroll
        for (int i = 0; i < 4; ++i)
#pragma unroll
            for (int j = 0; j < 4; ++j)
                acc[i][j] = __builtin_amdgcn_mfma_f32_16x16x32_bf16(af[i], bf[j], acc[i][j], 0, 0, 0);
        __syncthreads();
    }
#pragma unroll
    for (int i = 0; i < 4; ++i) {
        int rbase = m0 + wr * 64 + i * 16 + l4 * 4;
#pragma unroll
        for (int r = 0; r < 4; ++r) {
            int row = rbase + r;
            if (row < M) {
                float s = ns[row];
#pragma unroll
                for (int j = 0; j < 4; ++j) {
                    int col = n0 + wc * 64 + j * 16 + l15;
                    C[(size_t)row * 256 + col] = f2bf(acc[i][j][r] * s);
                }
            }
        }
    }
}

// ---------------- aggregate: out_bf16[n,:] = relu(nd[n] * sum_e h_bf16[src(e),:] + b) ----------------
__global__ __launch_bounds__(256) void k_agg(const unsigned short* __restrict__ h,
                                             const int* __restrict__ csr,
                                             const int* __restrict__ offs,
                                             const float* __restrict__ nd,
                                             const float* __restrict__ bias,
                                             unsigned short* __restrict__ out, int N) {
    int wave = threadIdx.x >> 6;
    int lane = threadIdx.x & 63;
    int node = blockIdx.x * 4 + wave;
    if (node >= N) return;
    int e0 = offs[node], e1 = offs[node + 1];
    float acc0 = 0.f, acc1 = 0.f, acc2 = 0.f, acc3 = 0.f;
    int e = e0;
    for (; e + 1 < e1; e += 2) {
        int s0 = csr[e], s1 = csr[e + 1];
        ushort4 a = *(const ushort4*)&h[(size_t)s0 * 256 + lane * 4];
        ushort4 b = *(const ushort4*)&h[(size_t)s1 * 256 + lane * 4];
        acc0 += bf2f(a.x); acc1 += bf2f(a.y); acc2 += bf2f(a.z); acc3 += bf2f(a.w);
        acc0 += bf2f(b.x); acc1 += bf2f(b.y); acc2 += bf2f(b.z); acc3 += bf2f(b.w);
    }
    if (e < e1) {
        int s0 = csr[e];
        ushort4 a = *(const ushort4*)&h[(size_t)s0 * 256 + lane * 4];
        acc0 += bf2f(a.x); acc1 += bf2f(a.y); acc2 += bf2f(a.z); acc3 += bf2f(a.w);
    }
    float sc = nd[node];
    float4 b4 = *(const float4*)&bias[lane * 4];
    ushort4 r;
    r.x = f2bf(fmaxf(fmaf(acc0, sc, b4.x), 0.f));
    r.y = f2bf(fmaxf(fmaf(acc1, sc, b4.y), 0.f));
    r.z = f2bf(fmaxf(fmaf(acc2, sc, b4.z), 0.f));
    r.w = f2bf(fmaxf(fmaf(acc3, sc, b4.w), 0.f));
    *(ushort4*)&out[(size_t)node * 256 + lane * 4] = r;
}

// ---------------- pool + linear + log_softmax ----------------
__global__ __launch_bounds__(256) void k_pool(const unsigned short* __restrict__ h,
                                              const int* __restrict__ gid,
                                              const float* __restrict__ Wlin,
                                              const float* __restrict__ blin,
                                              float* __restrict__ out, int N) {
    int g = blockIdx.x;
    int t = threadIdx.x;
    int s, e;
    {
        int lo = 0, hi = N;
        while (lo < hi) { int m = (lo + hi) >> 1; if (gid[m] < g) lo = m + 1; else hi = m; }
        s = lo;
        lo = s; hi = N;
        while (lo < hi) { int m = (lo + hi) >> 1; if (gid[m] < g + 1) lo = m + 1; else hi = m; }
        e = lo;
    }
    float acc = 0.f;
    for (int i = s; i < e; ++i) acc += bf2f(h[(size_t)i * 256 + t]);
    float cntf = (float)((e - s) > 0 ? (e - s) : 1);
    __shared__ float hg[256];
    hg[t] = acc / cntf;
    __syncthreads();
    if (t < 16) {
        float v = blin[t];
        for (int k = 0; k < 256; ++k) v = fmaf(hg[k], Wlin[k * 16 + t], v);
        float m = v;
#pragma unroll
        for (int off = 8; off; off >>= 1) m = fmaxf(m, __shfl_xor(m, off, 16));
        float ex = expf(v - m);
        float ssum = ex;
#pragma unroll
        for (int off = 8; off; off >>= 1) ssum += __shfl_xor(ssum, off, 16);
        out[g * 16 + t] = v - m - logf(ssum);
    }
}

extern "C" void kernel_launch(void* const* d_in, const int* in_sizes, int n_in,
                              void* d_out, int out_size, void* d_ws, size_t ws_size,
                              hipStream_t stream) {
    const float* feats   = (const float*)d_in[0];
    const int*   edge_src= (const int*)d_in[1];
    const int*   edge_dst= (const int*)d_in[2];
    const int*   gid     = (const int*)d_in[3];
    const float* W1 = (const float*)d_in[4];  const float* b1 = (const float*)d_in[5];
    const float* W2 = (const float*)d_in[6];  const float* b2 = (const float*)d_in[7];
    const float* W3 = (const float*)d_in[8];  const float* b3 = (const float*)d_in[9];
    const float* Wlin = (const float*)d_in[10]; const float* blin = (const float*)d_in[11];
    float* out = (float*)d_out;

    const int E = in_sizes[1];
    const int N = in_sizes[3];
    const int G = 256;

    size_t off = 0;
    auto alloc = [&](size_t bytes) -> void* {
        void* p = (char*)d_ws + off;
        off += (bytes + 255) & ~(size_t)255;
        return p;
    };
    int*   outd = (int*)alloc((size_t)N * 4);
    int*   ind  = (int*)alloc((size_t)N * 4);
    size_t zero_bytes = off;                    // zero the two atomic-counter arrays
    int*   part = (int*)alloc(256 * 4);
    int*   offs = (int*)alloc(((size_t)N + 1) * 4);
    float* ns   = (float*)alloc((size_t)N * 4);
    float* nd   = (float*)alloc((size_t)N * 4);
    int*   csr  = (int*)alloc((size_t)E * 4);
    unsigned short* Wt   = (unsigned short*)alloc((size_t)3 * 65536 * 2);
    unsigned short* fb   = (unsigned short*)alloc((size_t)N * HID * 2);  // feats bf16
    unsigned short* htmp = (unsigned short*)alloc((size_t)N * HID * 2);  // gemm out / gather src
    unsigned short* hb   = (unsigned short*)alloc((size_t)N * HID * 2);  // agg out / next gemm A
    // rank aliased onto hb: consumed by k_fill before hb's first write (layer-1 agg)
    int*   rank = (int*)hb;
    (void)ws_size;

    hipMemsetAsync(d_ws, 0, zero_bytes, stream);

    k_degree_rank<<<2048, 256, 0, stream>>>(edge_src, edge_dst, outd, ind, rank, E);
    k_scan_part<<<256, 256, 0, stream>>>(ind, part, N);
    k_scan_top<<<1, 256, 0, stream>>>(part);
    k_scan_fill<<<256, 256, 0, stream>>>(ind, outd, part, offs, ns, nd, N);
    k_fill<<<2048, 256, 0, stream>>>(edge_src, edge_dst, rank, offs, csr, E);
    k_cast<<<2048, 256, 0, stream>>>(feats, fb, N * HID / 4);
    k_wprep<<<256, 256, 0, stream>>>(W1, W2, W3, Wt);

    dim3 ggrid((N + 127) / 128, 2);
    int agg_blocks = (N + 3) / 4;

    // layer 1
    k_gemm_mf<<<ggrid, 256, 0, stream>>>(fb, Wt + 0 * 65536, ns, htmp, N);
    k_agg<<<agg_blocks, 256, 0, stream>>>(htmp, csr, offs, nd, b1, hb, N);
    // layer 2
    k_gemm_mf<<<ggrid, 256, 0, stream>>>(hb, Wt + 1 * 65536, ns, htmp, N);
    k_agg<<<agg_blocks, 256, 0, stream>>>(htmp, csr, offs, nd, b2, hb, N);
    // layer 3
    k_gemm_mf<<<ggrid, 256, 0, stream>>>(hb, Wt + 2 * 65536, ns, htmp, N);
    k_agg<<<agg_blocks, 256, 0, stream>>>(htmp, csr, offs, nd, b3, hb, N);

    k_pool<<<G, 256, 0, stream>>>(hb, gid, Wlin, blin, out, N);
    (void)out_size;
}